// Round 9
// baseline (178.272 us; speedup 1.0000x reference)
//
#include <hip/hip_runtime.h>
#include <utility>

// Gaunt tensor product via exact collapse of the S2-grid path to a sparse
// packed Gaunt tensor (computed on-device from Y_in/Y_out/qw).
//
// K0: per (i,j): G_row[k] = sum_p qw*Y_out[k,p]*Y_in[i,p]*Y_in[j,p],
//     packed + pre-scaled by 1/64 (the two 0.125 projection scales).
// K1: proj+Gaunt. Grid (256,3), block 256. Lane = (n_l = (t>>3)&7,
//     c_l = t&7); wave covers 8 n x 8 c x 2 c-groups. x and W both on the
//     VECTOR pipe with partial coalescing (8 unique addrs/instr); no LDS,
//     no barriers. Writes co[n][b][k][d] into d_out.
// K2: mix. 1 wave per (n,b). co rows via uniform s_load; Wout per-lane from
//     L2; in-place overwrite of d_out through an LDS transpose.

#define NN 2048

__host__ __device__ constexpr int l_of9(int i)  { return i < 1 ? 0 : (i < 4 ? 1 : 2); }
__host__ __device__ constexpr int l_of25(int k) { return k < 1 ? 0 : (k < 4 ? 1 : (k < 9 ? 2 : (k < 16 ? 3 : 4))); }
__host__ __device__ constexpr int iabs_(int v)  { return v < 0 ? -v : v; }

__host__ __device__ constexpr bool gmask(int k, int i, int j) {
    const int l3 = l_of25(k), m3 = k - l3 * l3 - l3;
    const int l1 = l_of9(i),  m1 = i - l1 * l1 - l1;
    const int l2 = l_of9(j),  m2 = j - l2 * l2 - l2;
    if (((l1 + l2 + l3) & 1) != 0) return false;
    if (l3 > l1 + l2 || l3 < iabs_(l1 - l2)) return false;
    const int am3 = iabs_(m3);
    return (am3 == iabs_(m1 + m2)) || (am3 == iabs_(m1 - m2));
}

struct GTab {
    int po[82];
    int pc[81];
    int kl[81][12];
    constexpr GTab() : po{}, pc{}, kl{} {
        int off = 0;
        for (int ij = 0; ij < 81; ++ij) {
            po[ij] = off;
            const int i = ij / 9, j = ij % 9;
            int cnum = 0;
            for (int k = 0; k < 25; ++k)
                if (gmask(k, i, j)) kl[ij][cnum++] = k;
            pc[ij] = cnum;
            off += (cnum + 3) & ~3;
        }
        po[81] = off;
    }
};
constexpr GTab GT{};

// ---------------------------------------------------------------------------
// K0: compute + pack G (pre-scaled by 1/64). Grid 81, 256 threads.
// ---------------------------------------------------------------------------
__global__ __launch_bounds__(256) void gaunt_pack_kernel(
    const float* __restrict__ Y_in, const float* __restrict__ Y_out,
    const float* __restrict__ qw, float* __restrict__ gp)
{
    const int ij = blockIdx.x;
    const int i = ij / 9, j = ij % 9;
    const int t = threadIdx.x;

    __shared__ float yy[780];
    __shared__ float ps[25][8];
    __shared__ float gr[25];

    for (int p = t; p < 780; p += 256)
        yy[p] = Y_in[i * 780 + p] * Y_in[j * 780 + p] * qw[p / 39];
    __syncthreads();

    if (t < 200) {
        const int k = t >> 3, s = t & 7;
        const float* yo = Y_out + k * 780;
        const int p1 = (s * 98 + 98 < 780) ? (s * 98 + 98) : 780;
        float a = 0.f;
        for (int p = s * 98; p < p1; ++p) a = fmaf(yy[p], yo[p], a);
        ps[k][s] = a;
    }
    __syncthreads();

    if (t < 25) {
        float a = 0.f;
#pragma unroll
        for (int s = 0; s < 8; ++s) a += ps[t][s];
        gr[t] = a;
    }
    __syncthreads();

    const int cntp = (GT.pc[ij] + 3) & ~3;
    if (t < cntp)
        gp[GT.po[ij] + t] = (t < GT.pc[ij]) ? gr[GT.kl[ij][t]] * 0.015625f : 0.f;
}

// ---------------------------------------------------------------------------
// Sparse in-register Gaunt with compile-time indices (gp loads uniform).
// ---------------------------------------------------------------------------
template <int IJ, int... Ts>
__device__ __forceinline__ void gaunt_apply(const float (&g)[12], float pij,
    float (&cov)[25], std::integer_sequence<int, Ts...>)
{
    ((cov[GT.kl[IJ][Ts]] = fmaf(g[Ts], pij, cov[GT.kl[IJ][Ts]])), ...);
}

template <int IJ>
__device__ __forceinline__ void gaunt_pair(const float* __restrict__ gp,
    const float (&c1)[9], const float (&c2)[9], float (&cov)[25])
{
    constexpr int cnt = GT.pc[IJ];
    if constexpr (cnt > 0) {
        constexpr int base = GT.po[IJ];
        constexpr int nv = (cnt + 3) / 4;
        const float pij = c1[IJ / 9] * c2[IJ % 9];
        float g[12];
#pragma unroll
        for (int q = 0; q < nv; ++q) {
            const float4 v = ((const float4*)(gp + base))[q];
            g[4 * q] = v.x; g[4 * q + 1] = v.y; g[4 * q + 2] = v.z; g[4 * q + 3] = v.w;
        }
        gaunt_apply<IJ>(g, pij, cov, std::make_integer_sequence<int, cnt>{});
    }
}

template <int I, int... Js>
__device__ __forceinline__ void gaunt_row(const float* __restrict__ gp,
    const float (&c1)[9], const float (&c2)[9], float (&cov)[25],
    std::integer_sequence<int, Js...>)
{
    (gaunt_pair<I * 9 + Js>(gp, c1, c2, cov), ...);
    __builtin_amdgcn_sched_barrier(0);   // bound live ranges per row
}

template <int... Is>
__device__ __forceinline__ void gaunt_all(const float* __restrict__ gp,
    const float (&c1)[9], const float (&c2)[9], float (&cov)[25],
    std::integer_sequence<int, Is...>)
{
    (gaunt_row<Is>(gp, c1, c2, cov, std::make_integer_sequence<int, 9>{}), ...);
}

// ---------------------------------------------------------------------------
// K1 body. Lane = (n_l, c_l); wave w covers c in {w*8..w*8+7} u {+32}.
// ---------------------------------------------------------------------------
template <int E1, int E2>
__device__ __forceinline__ void k1_body(
    const float* __restrict__ x1, const float* __restrict__ x2,
    const float* __restrict__ W1, const float* __restrict__ W2,
    const float* __restrict__ gp, float* __restrict__ out, int b)
{
    const int t   = threadIdx.x;
    const int c_l = t & 7;
    const int n_l = (t >> 3) & 7;
    const int w   = t >> 6;
    const int n   = blockIdx.x * 8 + n_l;

    const float4* px1 = (const float4*)(x1 + (size_t)n * 1152);
    const float4* px2 = (const float4*)(x2 + (size_t)n * 1152);
    const float* W1a = W1 + (size_t)b * 12288;
    const float* W2a = W2 + (size_t)b * 12288;
    const int cc0 = w * 8 + c_l;
    const int cc1 = cc0 + 32;

    float a1[2][9], a2[2][9];
#pragma unroll
    for (int i = 0; i < 9; ++i) {
        a1[0][i] = 0.f; a1[1][i] = 0.f;
        a2[0][i] = 0.f; a2[1][i] = 0.f;
    }

#pragma unroll 1
    for (int mp = 0; mp < 32; ++mp) {
        // ---- x: 18 float4 loads, 8 unique addrs each (n-groups) ----
        float4 v1[9], v2[9];
#pragma unroll
        for (int q = 0; q < 9; ++q) v1[q] = px1[mp * 9 + q];
#pragma unroll
        for (int q = 0; q < 9; ++q) v2[q] = px2[mp * 9 + q];

        // ---- W: 24 dword loads, 8 consecutive floats/n-group, merged ----
        float w1r[2][3][2], w2r[2][3][2];
#pragma unroll
        for (int l = 0; l < 3; ++l)
#pragma unroll
            for (int mi = 0; mi < 2; ++mi) {
                const int o = (l * 64 + mp * 2 + mi) * 64;
                w1r[0][l][mi] = W1a[o + cc0];
                w1r[1][l][mi] = W1a[o + cc1];
                w2r[0][l][mi] = W2a[o + cc0];
                w2r[1][l][mi] = W2a[o + cc1];
            }

        float xs1[36], xs2[36];
#pragma unroll
        for (int q = 0; q < 9; ++q) {
            xs1[4*q] = v1[q].x; xs1[4*q+1] = v1[q].y;
            xs1[4*q+2] = v1[q].z; xs1[4*q+3] = v1[q].w;
            xs2[4*q] = v2[q].x; xs2[4*q+1] = v2[q].y;
            xs2[4*q+2] = v2[q].z; xs2[4*q+3] = v2[q].w;
        }

#pragma unroll
        for (int cg = 0; cg < 2; ++cg)
#pragma unroll
            for (int l = 0; l < 3; ++l) {
                const int s1 = ((l & 1) ^ E1) * 9 + l * l;
                const int s2 = ((l & 1) ^ E2) * 9 + l * l;
#pragma unroll
                for (int mi = 0; mi < 2; ++mi)
#pragma unroll
                    for (int ii = 0; ii <= 2 * l; ++ii) {
                        a1[cg][l*l+ii] = fmaf(xs1[18*mi + s1 + ii],
                                              w1r[cg][l][mi], a1[cg][l*l+ii]);
                        a2[cg][l*l+ii] = fmaf(xs2[18*mi + s2 + ii],
                                              w2r[cg][l][mi], a2[cg][l*l+ii]);
                    }
            }
    }

    // ---- per c-group: Gaunt (gp pre-scaled by 1/64) + store ----
#pragma unroll
    for (int cg = 0; cg < 2; ++cg) {
        float c1[9], c2[9];
#pragma unroll
        for (int i = 0; i < 9; ++i) { c1[i] = a1[cg][i]; c2[i] = a2[cg][i]; }

        float cov[25] = {0,0,0,0,0,0,0,0,0,0,0,0,0,0,0,0,0,0,0,0,0,0,0,0,0};
        gaunt_all(gp, c1, c2, cov, std::make_integer_sequence<int, 9>{});

        const int cc = cg ? cc1 : cc0;
        float* cob = out + ((size_t)n * 3 + b) * 1600 + cc;
#pragma unroll
        for (int k = 0; k < 25; ++k) cob[k * 64] = cov[k];
    }
}

__global__ __launch_bounds__(256, 3) void proj_gaunt_kernel(
    const float* __restrict__ x1, const float* __restrict__ x2,
    const float* __restrict__ W1, const float* __restrict__ W2,
    const float* __restrict__ gp, float* __restrict__ out)
{
    const int b = blockIdx.y;
    if (b == 0)      k1_body<0, 0>(x1, x2, W1, W2, gp, out, 0);
    else if (b == 1) k1_body<0, 1>(x1, x2, W1, W2, gp, out, 1);
    else             k1_body<1, 0>(x1, x2, W1, W2, gp, out, 2);
}

// ---------------------------------------------------------------------------
// K2: mix, 1 wave per (n,b). co rows via uniform s_load; W per-lane; LDS
// transpose for coalesced float4 stores; in-place on d_out.
// ---------------------------------------------------------------------------
__global__ __launch_bounds__(64, 6) void mix_kernel(
    const float* __restrict__ Wout, float* __restrict__ io)
{
    const int n = blockIdx.x;
    const int b = blockIdx.y;
    const int c = threadIdx.x;   // 0..63

    __shared__ float st[1600];

    const float* cob = io + ((size_t)n * 3 + b) * 1600;   // [k][d]
    const float* WoB = Wout + (size_t)b * 5 * 4096 + c;

    float acc[25];
#pragma unroll
    for (int k = 0; k < 25; ++k) acc[k] = 0.f;

#pragma unroll 1
    for (int dc = 0; dc < 16; ++dc) {
        const int d0 = dc * 4;
        float wr[5][4];
#pragma unroll
        for (int l3 = 0; l3 < 5; ++l3)
#pragma unroll
            for (int q = 0; q < 4; ++q)
                wr[l3][q] = WoB[(size_t)(l3 * 64 + d0 + q) * 64];

#pragma unroll
        for (int kg = 0; kg < 5; ++kg) {
#pragma unroll
            for (int kk = 0; kk < 5; ++kk) {
                const int k = kg * 5 + kk;
                const int l3 = l_of25(k);
                const float4 cv = *(const float4*)(cob + k * 64 + d0);
                acc[k] = fmaf(cv.x, wr[l3][0], acc[k]);
                acc[k] = fmaf(cv.y, wr[l3][1], acc[k]);
                acc[k] = fmaf(cv.z, wr[l3][2], acc[k]);
                acc[k] = fmaf(cv.w, wr[l3][3], acc[k]);
            }
            __builtin_amdgcn_sched_barrier(0);   // keep s_load bursts small
        }
    }

    // ---- transpose [d=c][k] -> linear [c][k] in LDS, then float4 stores ----
#pragma unroll
    for (int k = 0; k < 25; ++k) st[c * 25 + k] = acc[k] * 0.125f;
    __syncthreads();

    float* op = io + ((size_t)n * 3 + b) * 1600;
#pragma unroll
    for (int r = 0; r < 6; ++r) {
        const float4 v = *(const float4*)&st[(r * 64 + c) * 4];
        *(float4*)(op + (r * 64 + c) * 4) = v;
    }
    if (c < 16) {
        const float4 v = *(const float4*)&st[(384 + c) * 4];
        *(float4*)(op + (384 + c) * 4) = v;
    }
}

extern "C" void kernel_launch(void* const* d_in, const int* in_sizes, int n_in,
                              void* d_out, int out_size, void* d_ws, size_t ws_size,
                              hipStream_t stream) {
    const float* x1    = (const float*)d_in[0];
    const float* x2    = (const float*)d_in[1];
    const float* W1    = (const float*)d_in[2];
    const float* W2    = (const float*)d_in[3];
    const float* Wout  = (const float*)d_in[4];
    const float* Y_in  = (const float*)d_in[5];
    const float* Y_out = (const float*)d_in[6];
    const float* qw    = (const float*)d_in[7];
    float* outp = (float*)d_out;
    float* gp   = (float*)d_ws;

    gaunt_pack_kernel<<<81, 256, 0, stream>>>(Y_in, Y_out, qw, gp);
    proj_gaunt_kernel<<<dim3(NN / 8, 3), 256, 0, stream>>>(x1, x2, W1, W2, gp, outp);
    mix_kernel<<<dim3(NN, 3), 64, 0, stream>>>(Wout, outp);
}

// Round 10
// 173.752 us; speedup vs baseline: 1.0260x; 1.0260x over previous
//
#include <hip/hip_runtime.h>
#include <utility>

// Gaunt tensor product via exact collapse of the S2-grid path to a sparse
// packed Gaunt tensor (computed on-device from Y_in/Y_out/qw).
//
// K0: per (i,j): G_row[k] = sum_p qw*Y_out[k,p]*Y_in[i,p]*Y_in[j,p],
//     packed + pre-scaled by 1/64 (the two 0.125 projection scales).
// K1 (fused): grid (3, 512); block = 4 n x 1 branch, 256 thr, wave = n,
//     lane = c. x staged via global_load_lds (double-buffered 8-m chunks,
//     zero VALU staging), read as wave-uniform LDS broadcasts. W per-lane
//     coalesced. Gaunt in registers (gp via s_load). Mix fused through LDS
//     (co never leaves the CU). Coalesced float4 stores.

#define NN 2048

__host__ __device__ constexpr int l_of9(int i)  { return i < 1 ? 0 : (i < 4 ? 1 : 2); }
__host__ __device__ constexpr int l_of25(int k) { return k < 1 ? 0 : (k < 4 ? 1 : (k < 9 ? 2 : (k < 16 ? 3 : 4))); }
__host__ __device__ constexpr int iabs_(int v)  { return v < 0 ? -v : v; }

__host__ __device__ constexpr bool gmask(int k, int i, int j) {
    const int l3 = l_of25(k), m3 = k - l3 * l3 - l3;
    const int l1 = l_of9(i),  m1 = i - l1 * l1 - l1;
    const int l2 = l_of9(j),  m2 = j - l2 * l2 - l2;
    if (((l1 + l2 + l3) & 1) != 0) return false;
    if (l3 > l1 + l2 || l3 < iabs_(l1 - l2)) return false;
    const int am3 = iabs_(m3);
    return (am3 == iabs_(m1 + m2)) || (am3 == iabs_(m1 - m2));
}

struct GTab {
    int po[82];
    int pc[81];
    int kl[81][12];
    constexpr GTab() : po{}, pc{}, kl{} {
        int off = 0;
        for (int ij = 0; ij < 81; ++ij) {
            po[ij] = off;
            const int i = ij / 9, j = ij % 9;
            int cnum = 0;
            for (int k = 0; k < 25; ++k)
                if (gmask(k, i, j)) kl[ij][cnum++] = k;
            pc[ij] = cnum;
            off += (cnum + 3) & ~3;
        }
        po[81] = off;
    }
};
constexpr GTab GT{};

// ---------------------------------------------------------------------------
// K0: compute + pack G (pre-scaled by 1/64). Grid 81, 256 threads.
// ---------------------------------------------------------------------------
__global__ __launch_bounds__(256) void gaunt_pack_kernel(
    const float* __restrict__ Y_in, const float* __restrict__ Y_out,
    const float* __restrict__ qw, float* __restrict__ gp)
{
    const int ij = blockIdx.x;
    const int i = ij / 9, j = ij % 9;
    const int t = threadIdx.x;

    __shared__ float yy[780];
    __shared__ float ps[25][8];
    __shared__ float gr[25];

    for (int p = t; p < 780; p += 256)
        yy[p] = Y_in[i * 780 + p] * Y_in[j * 780 + p] * qw[p / 39];
    __syncthreads();

    if (t < 200) {
        const int k = t >> 3, s = t & 7;
        const float* yo = Y_out + k * 780;
        const int p1 = (s * 98 + 98 < 780) ? (s * 98 + 98) : 780;
        float a = 0.f;
        for (int p = s * 98; p < p1; ++p) a = fmaf(yy[p], yo[p], a);
        ps[k][s] = a;
    }
    __syncthreads();

    if (t < 25) {
        float a = 0.f;
#pragma unroll
        for (int s = 0; s < 8; ++s) a += ps[t][s];
        gr[t] = a;
    }
    __syncthreads();

    const int cntp = (GT.pc[ij] + 3) & ~3;
    if (t < cntp)
        gp[GT.po[ij] + t] = (t < GT.pc[ij]) ? gr[GT.kl[ij][t]] * 0.015625f : 0.f;
}

// ---------------------------------------------------------------------------
// Sparse in-register Gaunt with compile-time indices (gp loads uniform).
// ---------------------------------------------------------------------------
template <int IJ, int... Ts>
__device__ __forceinline__ void gaunt_apply(const float (&g)[12], float pij,
    float (&cov)[25], std::integer_sequence<int, Ts...>)
{
    ((cov[GT.kl[IJ][Ts]] = fmaf(g[Ts], pij, cov[GT.kl[IJ][Ts]])), ...);
}

template <int IJ>
__device__ __forceinline__ void gaunt_pair(const float* __restrict__ gp,
    const float (&c1)[9], const float (&c2)[9], float (&cov)[25])
{
    constexpr int cnt = GT.pc[IJ];
    if constexpr (cnt > 0) {
        constexpr int base = GT.po[IJ];
        constexpr int nv = (cnt + 3) / 4;
        const float pij = c1[IJ / 9] * c2[IJ % 9];
        float g[12];
#pragma unroll
        for (int q = 0; q < nv; ++q) {
            const float4 v = ((const float4*)(gp + base))[q];
            g[4 * q] = v.x; g[4 * q + 1] = v.y; g[4 * q + 2] = v.z; g[4 * q + 3] = v.w;
        }
        gaunt_apply<IJ>(g, pij, cov, std::make_integer_sequence<int, cnt>{});
    }
}

template <int I, int... Js>
__device__ __forceinline__ void gaunt_row(const float* __restrict__ gp,
    const float (&c1)[9], const float (&c2)[9], float (&cov)[25],
    std::integer_sequence<int, Js...>)
{
    (gaunt_pair<I * 9 + Js>(gp, c1, c2, cov), ...);
    __builtin_amdgcn_sched_barrier(0);   // bound live ranges per row
}

template <int... Is>
__device__ __forceinline__ void gaunt_all(const float* __restrict__ gp,
    const float (&c1)[9], const float (&c2)[9], float (&cov)[25],
    std::integer_sequence<int, Is...>)
{
    (gaunt_row<Is>(gp, c1, c2, cov, std::make_integer_sequence<int, 9>{}), ...);
}

// ---------------------------------------------------------------------------
// global_load_lds helper: 16B per lane, dest = lds_base + lane*16.
// ---------------------------------------------------------------------------
typedef __attribute__((address_space(1))) const unsigned int gas_u32;
typedef __attribute__((address_space(3))) unsigned int las_u32;
__device__ __forceinline__ void gll16(const void* g, void* l) {
    __builtin_amdgcn_global_load_lds((gas_u32*)g, (las_u32*)l, 16, 0, 0);
}

// ---------------------------------------------------------------------------
// K1 body. LDS (28.7KB union):
//   staging: [buf(2)][arr(2)][n_l(4)][144] floats  (9216 B)
//   co:      per-wave 1792 floats [d(64)][28]      (28672 B)
// Chunk = 8 m = 144 floats per (arr, n). 288 16B-groups per chunk.
// ---------------------------------------------------------------------------
template <int E1, int E2>
__device__ __forceinline__ void k1_body(
    const float* __restrict__ x1, const float* __restrict__ x2,
    const float* __restrict__ W1, const float* __restrict__ W2,
    const float* __restrict__ Wout, const float* __restrict__ gp,
    float* __restrict__ out, float* smemf, int b)
{
    const int t  = threadIdx.x;
    const int c  = t & 63;
    const int w  = t >> 6;
    const int n0 = blockIdx.y * 4;
    const int n  = n0 + w;

    char* smem = (char*)smemf;

    // ---- staging issue (one chunk, one buffer) ----
    auto stage = [&](int mc, int buf) {
        {
            const int g   = t;                 // group 0..255
            const int arr = g / 144;
            const int gg  = g - arr * 144;
            const int n_l = gg / 36;
            const int r4  = (gg - n_l * 36) * 4;
            const float* src = (arr ? x2 : x1) +
                (size_t)(n0 + n_l) * 1152 + mc * 144 + r4;
            char* dst = smem + buf * 4608 + (t & ~63) * 16;  // wave-uniform
            gll16(src, dst);
        }
        if (t < 32) {                          // groups 256..287 (arr1, n_l 3)
            const int gg  = 256 + t - 144;     // 112..143
            const int r4  = (gg - 108) * 4;    // 16..140
            const float* src = x2 + (size_t)(n0 + 3) * 1152 + mc * 144 + r4;
            char* dst = smem + buf * 4608 + 4096;
            gll16(src, dst);
        }
    };

    const float* W1b = W1 + (size_t)b * 12288 + c;
    const float* W2b = W2 + (size_t)b * 12288 + c;

    float a1[9] = {0,0,0,0,0,0,0,0,0};
    float a2[9] = {0,0,0,0,0,0,0,0,0};

    stage(0, 0);
    __syncthreads();

#pragma unroll 1
    for (int mc = 0; mc < 8; ++mc) {
        const int buf = mc & 1;
        if (mc < 7) stage(mc + 1, buf ^ 1);    // prefetch next chunk

        const float* xb1 = smemf + buf * 1152 + w * 144;        // arr 0
        const float* xb2 = smemf + buf * 1152 + 576 + w * 144;  // arr 1

#pragma unroll 1
        for (int mh = 0; mh < 2; ++mh) {
            float w1r[3][4], w2r[3][4];
#pragma unroll
            for (int l = 0; l < 3; ++l)
#pragma unroll
                for (int mm = 0; mm < 4; ++mm) {
                    const int o = (l * 64 + mc * 8 + mh * 4 + mm) * 64;
                    w1r[l][mm] = W1b[o];
                    w2r[l][mm] = W2b[o];
                }
#pragma unroll
            for (int mm = 0; mm < 4; ++mm) {
                const float* r1 = xb1 + (mh * 4 + mm) * 18;
                const float* r2 = xb2 + (mh * 4 + mm) * 18;
                float xv1[18], xv2[18];
#pragma unroll
                for (int q = 0; q < 9; ++q) {
                    const float2 v1 = *(const float2*)(r1 + q * 2);
                    const float2 v2 = *(const float2*)(r2 + q * 2);
                    xv1[2*q] = v1.x; xv1[2*q+1] = v1.y;
                    xv2[2*q] = v2.x; xv2[2*q+1] = v2.y;
                }
#pragma unroll
                for (int l = 0; l < 3; ++l) {
                    const int O1 = ((l & 1) ^ E1) * 9 + l * l;
                    const int O2 = ((l & 1) ^ E2) * 9 + l * l;
#pragma unroll
                    for (int ii = 0; ii <= 2 * l; ++ii) {
                        a1[l*l+ii] = fmaf(xv1[O1 + ii], w1r[l][mm], a1[l*l+ii]);
                        a2[l*l+ii] = fmaf(xv2[O2 + ii], w2r[l][mm], a2[l*l+ii]);
                    }
                }
            }
        }
        __syncthreads();   // staged chunk mc+1 complete; buffers swap safe
    }

    // ---- Gaunt in registers (gp pre-scaled by 1/64, uniform s_loads) ----
    float cov[25] = {0,0,0,0,0,0,0,0,0,0,0,0,0,0,0,0,0,0,0,0,0,0,0,0,0};
    gaunt_all(gp, a1, a2, cov, std::make_integer_sequence<int, 9>{});

    // ---- co exchange + mix, all intra-wave (no barriers) ----
    float* colw = smemf + w * 1792;            // [d][28]
#pragma unroll
    for (int k = 0; k < 25; ++k) colw[c * 28 + k] = cov[k];

    const float* WoB = Wout + (size_t)b * 20480 + c;
    float acc[25];
#pragma unroll
    for (int k = 0; k < 25; ++k) acc[k] = 0.f;

#pragma unroll 1
    for (int dc = 0; dc < 16; ++dc) {
        float wv[5][4];
#pragma unroll
        for (int l3 = 0; l3 < 5; ++l3)
#pragma unroll
            for (int dd = 0; dd < 4; ++dd)
                wv[l3][dd] = WoB[(l3 * 64 + dc * 4 + dd) * 64];
#pragma unroll
        for (int dd = 0; dd < 4; ++dd) {
            const float* row = colw + (dc * 4 + dd) * 28;
            float f[28];
#pragma unroll
            for (int q = 0; q < 7; ++q) {
                const float4 v = *(const float4*)(row + q * 4);
                f[4*q] = v.x; f[4*q+1] = v.y; f[4*q+2] = v.z; f[4*q+3] = v.w;
            }
#pragma unroll
            for (int k = 0; k < 25; ++k)
                acc[k] = fmaf(f[k], wv[l_of25(k)][dd], acc[k]);
        }
    }

    // ---- restage own-wave region for coalesced stores ----
#pragma unroll
    for (int k = 0; k < 25; ++k) colw[c * 25 + k] = acc[k] * 0.125f;

    float* on = out + ((size_t)n * 3 + b) * 1600;
#pragma unroll
    for (int r = 0; r < 6; ++r) {
        const float4 v = *(const float4*)&colw[r * 256 + c * 4];
        *(float4*)&on[r * 256 + c * 4] = v;
    }
    on[1536 + c] = colw[1536 + c];
}

__global__ __launch_bounds__(256, 4) void fused_kernel(
    const float* __restrict__ x1, const float* __restrict__ x2,
    const float* __restrict__ W1, const float* __restrict__ W2,
    const float* __restrict__ Wout, const float* __restrict__ gp,
    float* __restrict__ out)
{
    __shared__ __align__(16) float smemf[7168];   // 28672 B union
    const int b = blockIdx.x;
    if (b == 0)      k1_body<0, 0>(x1, x2, W1, W2, Wout, gp, out, smemf, 0);
    else if (b == 1) k1_body<0, 1>(x1, x2, W1, W2, Wout, gp, out, smemf, 1);
    else             k1_body<1, 0>(x1, x2, W1, W2, Wout, gp, out, smemf, 2);
}

extern "C" void kernel_launch(void* const* d_in, const int* in_sizes, int n_in,
                              void* d_out, int out_size, void* d_ws, size_t ws_size,
                              hipStream_t stream) {
    const float* x1    = (const float*)d_in[0];
    const float* x2    = (const float*)d_in[1];
    const float* W1    = (const float*)d_in[2];
    const float* W2    = (const float*)d_in[3];
    const float* Wout  = (const float*)d_in[4];
    const float* Y_in  = (const float*)d_in[5];
    const float* Y_out = (const float*)d_in[6];
    const float* qw    = (const float*)d_in[7];
    float* outp = (float*)d_out;
    float* gp   = (float*)d_ws;

    gaunt_pack_kernel<<<81, 256, 0, stream>>>(Y_in, Y_out, qw, gp);
    fused_kernel<<<dim3(3, NN / 4), 256, 0, stream>>>(x1, x2, W1, W2, Wout, gp, outp);
}